// Round 6
// baseline (184.898 us; speedup 1.0000x reference)
//
#include <hip/hip_runtime.h>
#include <hip/hip_bf16.h>

// ---------------------------------------------------------------------------
// NHRepNet fused forward, Round 20: poly-log softplus (1 trans, was 2).
//
// Established (R1-R19):
//  - R17/R19 (96-pt, kk-sliced A/B stagger, 8 waves x 32ch): 103.4-104.4us,
//    Mfma+VALU ~87%. Interleave proven (+12 vs R14 phase-serial).
//  - R19 showed the ~6MB extra WRITE is a fixed ~3-reg once-per-block spill
//    (~1us) — NOT prefetch-induced; not worth chasing.
//  - Stream model @104us: LDS-B ~55-70us (3.7GB at measured 85B/cyc/CU b128
//    rate) CO-CRITICAL with VALU ~54us (trans-heavy); MFMA 35us. LDS bytes
//    structurally fixed: Gch=4 closed (R18 reg wall), fp8 act closed
//    (accuracy). Remaining levers = VALU shaving.
//
// R20 = R19 with softplus_t2 rewritten: log2(1+e) -> cubic-through-origin
// poly on e in [0,1]: e*(1.4427 + e*(-0.64838 + e*0.20568)), max err ~0.004
// t2-units = 2.8e-5 output units (~50x below bf16 act-storage noise; exact
// at e=0,1). Per act: 2 trans + 3 VALU -> 1 trans + 5 VALU. Trans lane-ops
// halve (~-9us issue), +2 cheap VALU (~+4us). Single-point change in the
// shared helper; all else byte-identical to R19.
// Gates: absmax stays 0.03125; dur 97-101us; VALUBusy -3..-5 pts.
// ---------------------------------------------------------------------------

using bf16x8 = __attribute__((ext_vector_type(8))) __bf16;
using f32x4  = __attribute__((ext_vector_type(4))) float;

#define LDA 264   // padded activation row stride (bf16)

#define OFFW0 0
#define OFFW1 8192
#define OFFW7 401408
#define WSB_BYTE_OFF 811008   // fp32 bias region
#define OFFB7 1792            // L0..L6 at l*256; L7 at 1792 (16 floats, padded)

#define SCALE_T2 144.26950408889634f      // 100*log2(e)
#define INV_SQRT2 0.70710678118654752f
#define LN2_100 0.0069314718055994531f    // ln2/100

__device__ __forceinline__ float fast_exp2(float x) {
#if __has_builtin(__builtin_amdgcn_exp2f)
    return __builtin_amdgcn_exp2f(x);
#else
    return exp2f(x);
#endif
}

// a2 = max(t2,0) + log2(1 + 2^-|t2|)   (t2-domain; scales folded into weights)
// log2(1+e), e in [0,1], replaced by cubic through origin:
//   e*(1.4427 + e*(-0.64838 + e*0.20568)); |err| <= ~0.004 t2-units,
//   ~2.8e-5 in output units — far below bf16 activation-storage noise.
//   Exact at e=0 (large |t2|) and e=1 (t2=0). 1 trans + 5 VALU (was 2+3).
__device__ __forceinline__ float softplus_t2(float t2) {
    float e = fast_exp2(-fabsf(t2));          // |.| and neg fold into VOP3 mods
    float p = __builtin_fmaf(e, 0.20568f, -0.64838f);
    p = __builtin_fmaf(e, p, 1.4427f);
    return fmaxf(t2, 0.0f) + e * p;
}

__device__ __forceinline__ unsigned short bf16_rne(float f) {
    unsigned int u = __float_as_uint(f);
    unsigned int r = u + 0x7FFFu + ((u >> 16) & 1u);
    return (unsigned short)(r >> 16);
}

// ---------------------------------------------------------------------------
// Plain MFMA half (layer 0 only, KK=1). Wave owns ch [wave*32, wave*32+32).
// ---------------------------------------------------------------------------
template <int KK, int NTG>
__device__ __forceinline__ void mfma_group(
    const unsigned short* __restrict__ wfrag,
    const float* __restrict__ bias,
    const unsigned short* act,
    f32x4 (&acc)[2][NTG], int wave, int lane)
{
    const int quad = lane >> 4;
    const int l15  = lane & 15;

#pragma unroll
    for (int i = 0; i < 2; ++i) {
        const int chb = (wave * 2 + i) * 16 + quad * 4;
        const float4 b4 = *(const float4*)(bias + chb);
#pragma unroll
        for (int nt = 0; nt < NTG; ++nt)
            acc[i][nt] = f32x4{b4.x, b4.y, b4.z, b4.w};
    }

    const unsigned short* wbase = wfrag + (wave * 2 * KK * 64 + lane) * 8;

#pragma unroll
    for (int kk = 0; kk < KK; ++kk) {
        bf16x8 bfr[NTG];
#pragma unroll
        for (int nt = 0; nt < NTG; ++nt)
            bfr[nt] = *(const bf16x8*)(act + (nt * 16 + l15) * LDA + kk * 32 + quad * 8);
#pragma unroll
        for (int i = 0; i < 2; ++i) {
            bf16x8 afr = *(const bf16x8*)(wbase + (i * KK + kk) * 512);
#pragma unroll
            for (int nt = 0; nt < NTG; ++nt)
                acc[i][nt] = __builtin_amdgcn_mfma_f32_16x16x32_bf16(afr, bfr[nt], acc[i][nt], 0, 0, 0);
        }
    }
}

// Full epilogue of a group (used where no mfma to hide under).
template <int NTG>
__device__ __forceinline__ void epi_group_full(
    f32x4 (&acc)[2][NTG], unsigned short* act, const float* xst,
    int wave, int lane, bool splice)
{
    const int quad = lane >> 4;
    const int l15  = lane & 15;
#pragma unroll
    for (int i = 0; i < 2; ++i) {
        const int chb = (wave * 2 + i) * 16 + quad * 4;
#pragma unroll
        for (int nt = 0; nt < NTG; ++nt) {
            const int pt = nt * 16 + l15;
            float vv[4];
#pragma unroll
            for (int r = 0; r < 4; ++r)
                vv[r] = softplus_t2(acc[i][nt][r]);
            if (splice && chb == 252) {
                vv[1] = xst[pt * 4 + 0];
                vv[2] = xst[pt * 4 + 1];
                vv[3] = xst[pt * 4 + 2];
            }
            __hip_bfloat162 p01 = __float22bfloat162_rn(float2{vv[0], vv[1]});
            __hip_bfloat162 p23 = __float22bfloat162_rn(float2{vv[2], vv[3]});
            uint2 pk;
            pk.x = *(unsigned int*)&p01;
            pk.y = *(unsigned int*)&p23;
            *(uint2*)(act + pt * LDA + chb) = pk;
        }
    }
}

// ---------------------------------------------------------------------------
// Staggered region: build accX = W.actX + b while retiring accY (other
// group's previous-layer preacts) one slice per kk step (6 slices, kk 0..5).
// Order per kk: bfr ds_reads -> afr loads -> slice VALU (in load shadow) ->
// 6 MFMAs. No forced prefetch: compiler pipelines within its reg budget.
// ---------------------------------------------------------------------------
template <int KK, int NTG>
__device__ __forceinline__ void stag_region(
    const unsigned short* __restrict__ wfrag,
    const float* __restrict__ bias,
    const unsigned short* __restrict__ actX,
    unsigned short* actY,
    f32x4 (&accX)[2][NTG], f32x4 (&accY)[2][NTG],
    const float* xstY, bool splice, int wave, int lane)
{
    const int quad = lane >> 4;
    const int l15  = lane & 15;

#pragma unroll
    for (int i = 0; i < 2; ++i) {
        const int chb = (wave * 2 + i) * 16 + quad * 4;
        const float4 b4 = *(const float4*)(bias + chb);
#pragma unroll
        for (int nt = 0; nt < NTG; ++nt)
            accX[i][nt] = f32x4{b4.x, b4.y, b4.z, b4.w};
    }

    const unsigned short* wbase = wfrag + (wave * 2 * KK * 64 + lane) * 8;

#pragma unroll
    for (int kk = 0; kk < KK; ++kk) {
        bf16x8 bfr[NTG];
#pragma unroll
        for (int nt = 0; nt < NTG; ++nt)
            bfr[nt] = *(const bf16x8*)(actX + (nt * 16 + l15) * LDA + kk * 32 + quad * 8);

        bf16x8 a0 = *(const bf16x8*)(wbase + kk * 512);
        bf16x8 a1 = *(const bf16x8*)(wbase + (KK + kk) * 512);

        if (kk < 2 * NTG) {   // one retired slice of group Y (compile-time idx)
            const int i  = kk & 1;       // constant under full unroll
            const int nt = kk >> 1;
            const int chb = (wave * 2 + i) * 16 + quad * 4;
            const int pt  = nt * 16 + l15;
            float vv[4];
#pragma unroll
            for (int r = 0; r < 4; ++r)
                vv[r] = softplus_t2(accY[i][nt][r]);
            if (splice && chb == 252) {   // ch 253..255 <- raw x
                vv[1] = xstY[pt * 4 + 0];
                vv[2] = xstY[pt * 4 + 1];
                vv[3] = xstY[pt * 4 + 2];
            }
            __hip_bfloat162 p01 = __float22bfloat162_rn(float2{vv[0], vv[1]});
            __hip_bfloat162 p23 = __float22bfloat162_rn(float2{vv[2], vv[3]});
            uint2 pk;
            pk.x = *(unsigned int*)&p01;
            pk.y = *(unsigned int*)&p23;
            *(uint2*)(actY + pt * LDA + chb) = pk;
        }

#pragma unroll
        for (int nt = 0; nt < NTG; ++nt)
            accX[0][nt] = __builtin_amdgcn_mfma_f32_16x16x32_bf16(a0, bfr[nt], accX[0][nt], 0, 0, 0);
#pragma unroll
        for (int nt = 0; nt < NTG; ++nt)
            accX[1][nt] = __builtin_amdgcn_mfma_f32_16x16x32_bf16(a1, bfr[nt], accX[1][nt], 0, 0, 0);
    }
}

// ---------------------------------------------------------------------------
// Layer 7 (256->8) for one 16-pt row block at row0; reduce + CSG + store.
// ---------------------------------------------------------------------------
__device__ __forceinline__ void l7_part(
    const unsigned short* act, const unsigned short* __restrict__ w7,
    const float* __restrict__ wsB, float* __restrict__ out,
    int row0, int ptg0, int npts, int lane)
{
    const int quad = lane >> 4, l15 = lane & 15;
    const float4 b4 = *(const float4*)(wsB + OFFB7 + quad * 4);  // quads>=2: zeros
    f32x4 acc = f32x4{b4.x, b4.y, b4.z, b4.w};
#pragma unroll
    for (int kk = 0; kk < 8; ++kk) {
        bf16x8 bfr = *(const bf16x8*)(act + (row0 + l15) * LDA + kk * 32 + quad * 8);
        bf16x8 afr = *(const bf16x8*)(w7 + (kk * 64 + lane) * 8);
        acc = __builtin_amdgcn_mfma_f32_16x16x32_bf16(afr, bfr, acc, 0, 0, 0);
    }
    // quad0 lanes hold ch0-3, quad1 ch4-7 for pt = row0+l15
    float u0 = __shfl(acc[0], l15 + 16);
    float u1 = __shfl(acc[1], l15 + 16);
    float u2 = __shfl(acc[2], l15 + 16);
    float u3 = __shfl(acc[3], l15 + 16);
    if (quad == 0) {
        const int ptg = ptg0 + l15;
        if (ptg < npts) {
            const float v0 = acc[0], v1 = acc[1], v2 = acc[2], v3 = acc[3];
            const float v4 = u0, v5 = u1, v6 = u2, v7 = u3;
            const float m23   = fminf(v2, v3);
            const float m67   = fmaxf(v6, v7);
            const float m4567 = fminf(fminf(v4, v5), m67);
            const float h     = fmaxf(fmaxf(v0, v1), fmaxf(m23, m4567));
            float* o = out + (long)ptg * 9;
            o[0] = h;
            o[1] = v0; o[2] = v1; o[3] = v2; o[4] = v3;
            o[5] = v4; o[6] = v5; o[7] = v6; o[8] = v7;
        }
    }
}

// ---------------------------------------------------------------------------
// Full network for one tile of 2*NTG*16 points (NTG=3 -> 96, NTG=1 -> 32),
// two staggered in-place groups A (rows 0..NTG*16) and B (rest). Schedule:
//   stage; bar
//   mfma_A(0); bar
//   mfma_B(0); epi_A(0); bar
//   l=1..6:  stag[mfma_A(l) + slices of accB(l-1)]; bar
//            stag[mfma_B(l) + slices of accA(l)];   bar
//   [L7(A) || epi_B(6)]; bar;  L7(B)
// ---------------------------------------------------------------------------
template <int NTG>
__device__ __forceinline__ void run_net(
    const float* __restrict__ x, float* __restrict__ out,
    const unsigned short* __restrict__ wsW, const float* __restrict__ wsB,
    unsigned short* act, float* xst,
    int base_pt, int npts, int tid)
{
    const int wave = tid >> 6, lane = tid & 63;

    // stage x into act channels 0..2, zero-pad to 32 (K-pad for layer 0)
    for (int i = tid; i < 2 * NTG * 16 * 32; i += 512) {
        const int pt = i >> 5, ch = i & 31;
        const int ptg = base_pt + pt;
        float v = 0.0f;
        if (ch < 3 && ptg < npts) v = x[ptg * 3 + ch];
        act[pt * LDA + ch] = bf16_rne(v);
        if (ch < 4) xst[pt * 4 + ch] = (ch < 3) ? v : 0.0f;
    }
    __syncthreads();

    unsigned short* actA = act;
    unsigned short* actB = act + NTG * 16 * LDA;
    const float* xstA = xst;
    const float* xstB = xst + NTG * 16 * 4;

    f32x4 accA[2][NTG], accB[2][NTG];

    // layer 0 (KK=1, tiny): A alone, then B with serial epi_A
    mfma_group<1, NTG>(wsW + OFFW0, wsB, actA, accA, wave, lane);
    __syncthreads();
    mfma_group<1, NTG>(wsW + OFFW0, wsB, actB, accB, wave, lane);
    epi_group_full<NTG>(accA, actA, xstA, wave, lane, false);
    __syncthreads();

    // layers 1..6, two staggered regions each
#pragma unroll 1
    for (int l = 1; l <= 6; ++l) {
        const unsigned short* Wl = wsW + OFFW1 + (l - 1) * 65536;
        const float* bl = wsB + l * 256;

        // mfma_A(l) + retire accB(l-1)  (splice when l-1 == 3)
        stag_region<8, NTG>(Wl, bl, actA, actB, accA, accB, xstB, l == 4, wave, lane);
        __syncthreads();

        // mfma_B(l) + retire accA(l)    (splice when l == 3)
        stag_region<8, NTG>(Wl, bl, actB, actA, accB, accA, xstA, l == 3, wave, lane);
        __syncthreads();
    }

    // [L7(A) || epi_B(6)]: actA finalized last region; epi writes actB only.
    if (wave < NTG)
        l7_part(act, wsW + OFFW7, wsB, out, wave * 16, base_pt + wave * 16, npts, lane);
    epi_group_full<NTG>(accB, actB, xstB, wave, lane, false);
    __syncthreads();

    // L7(B)
    if (wave < NTG)
        l7_part(act, wsW + OFFW7, wsB, out,
                NTG * 16 + wave * 16, base_pt + NTG * 16 + wave * 16, npts, lane);
}

__global__ __launch_bounds__(512, 4)
void nhrep_main(const float* __restrict__ x, float* __restrict__ out,
                const unsigned short* __restrict__ wsW,
                const float* __restrict__ wsB, int npts, int nbig)
{
    __shared__ unsigned short act[96 * LDA];   // 50688 B
    __shared__ float xst[96 * 4];              // 1536 B -> 52224 B total
    const int b = blockIdx.x;
    if (b < nbig) {
        run_net<3>(x, out, wsW, wsB, act, xst, b * 96, npts, threadIdx.x);
    } else {
        run_net<1>(x, out, wsW, wsB, act, xst,
                   nbig * 96 + (b - nbig) * 32, npts, threadIdx.x);
    }
}

// ---------------------------------------------------------------------------
// Fused prepack with scale folding (proven since R4, identity k-mapping).
// Frag (mt,kk,lane,j) = scale(l,k) * W^T[mt*16+(lane&15)][kk*32+(lane>>4)*8+j]
// ---------------------------------------------------------------------------
struct PackArgs {
    const float* W[8];
    const float* b[8];
};

#define TOTAL_FRAGS 50688
#define TOTAL_BIAS  1808

__global__ void prepack_all(PackArgs args, unsigned short* __restrict__ dstW,
                            float* __restrict__ dstB)
{
    const int t = blockIdx.x * blockDim.x + threadIdx.x;
    const int FB[9]  = {0, 1024, 9216, 17408, 25600, 33792, 41984, 50176, 50688};
    const int KKs[8] = {1, 8, 8, 8, 8, 8, 8, 8};
    const int ind[8] = {3, 256, 256, 256, 256, 256, 256, 256};
    const int outd[8]= {256, 256, 256, 253, 256, 256, 256, 8};

    if (t < TOTAL_FRAGS) {
        int l = 0;
        while (t >= FB[l + 1]) ++l;
        const int f    = t - FB[l];
        const int lane = f & 63;
        const int kk   = (f >> 6) % KKs[l];
        const int mt   = f / (64 * KKs[l]);
        const int o    = mt * 16 + (lane & 15);
        const int kb   = kk * 32 + (lane >> 4) * 8;
        const float* W = args.W[l];
        const int in_d = ind[l], out_d = outd[l];

        unsigned short v[8];
#pragma unroll
        for (int j = 0; j < 8; ++j) {
            const int k = kb + j;
            float w = 0.0f;
            if (k < in_d && o < out_d) {
                float sc = 1.0f;
                if (l == 0) sc = SCALE_T2;
                else if (l == 4) sc = (k < 253) ? INV_SQRT2 : (SCALE_T2 * INV_SQRT2);
                else if (l == 7) sc = LN2_100;
                w = W[k * out_d + o] * sc;
            }
            unsigned int u = __float_as_uint(w);
            v[j] = (unsigned short)((u + 0x7FFFu + ((u >> 16) & 1u)) >> 16);
        }
        uint4 p;
        p.x = (unsigned int)v[0] | ((unsigned int)v[1] << 16);
        p.y = (unsigned int)v[2] | ((unsigned int)v[3] << 16);
        p.z = (unsigned int)v[4] | ((unsigned int)v[5] << 16);
        p.w = (unsigned int)v[6] | ((unsigned int)v[7] << 16);
        *(uint4*)(dstW + (long)t * 8) = p;
    } else if (t < TOTAL_FRAGS + TOTAL_BIAS) {
        const int u = t - TOTAL_FRAGS;
        const int l = (u < 1792) ? (u >> 8) : 7;
        const int idx = (l < 7) ? (u & 255) : (u - 1792);
        const float sc = (l < 7) ? SCALE_T2 : 1.0f;   // b7 stays in output units
        dstB[u] = (idx < outd[l]) ? args.b[l][idx] * sc : 0.0f;
    }
}

extern "C" void kernel_launch(void* const* d_in, const int* in_sizes, int n_in,
                              void* d_out, int out_size, void* d_ws, size_t ws_size,
                              hipStream_t stream)
{
    const float* x = (const float*)d_in[0];
    unsigned short* wsW = (unsigned short*)d_ws;
    float* wsB = (float*)((char*)d_ws + WSB_BYTE_OFF);

    PackArgs pa;
    for (int l = 0; l < 8; ++l) {
        pa.W[l] = (const float*)d_in[1 + 2 * l];
        pa.b[l] = (const float*)d_in[2 + 2 * l];
    }
    const int ptot = TOTAL_FRAGS + TOTAL_BIAS;
    prepack_all<<<(ptot + 255) / 256, 256, 0, stream>>>(pa, wsW, wsB);

    const int npts = in_sizes[0] / 3;            // 100000
    // Mixed grid: 96-pt blocks for the bulk, 32-pt blocks for the drain tail.
    int nbig, nsmall;
    const int tail_pts = 16384;
    if (npts > tail_pts) {
        nbig = (npts - tail_pts + 95) / 96;      // 871
        const int base_small = nbig * 96;
        nsmall = (npts - base_small + 31) / 32;  // 512
    } else {
        nbig = 0;
        nsmall = (npts + 31) / 32;
    }
    nhrep_main<<<nbig + nsmall, 512, 0, stream>>>(x, (float*)d_out, wsW, wsB,
                                                  npts, nbig);
}

// Round 7
// 182.559 us; speedup vs baseline: 1.0128x; 1.0128x over previous
//
#include <hip/hip_runtime.h>
#include <hip/hip_bf16.h>

// ---------------------------------------------------------------------------
// NHRepNet fused forward, Round 21: LDS-only barriers (no vmcnt drain).
//
// Established (R1-R20):
//  - R17/R19 (96-pt, kk-sliced A/B stagger): 103.4-104.4us. Interleave proven.
//  - R20 (poly softplus): VALUBusy 52.5->41.4 (work really removed) but dur
//    105.6 — NULL. VALU is NOT the critical path. Critical residue ~25% =
//    LDS pipe + barrier drains.
//  - __syncthreads emits s_waitcnt vmcnt(0) lgkmcnt(0) before s_barrier
//    (m97's ~20% stall), 16x/block -> kills cross-region weight prefetch.
//    Hazard audit: ALL inter-wave hazards here are LDS-side (epi writes ->
//    ds_reads; stage -> L0; xst). Weight loads are wave-local. vmcnt NEVER
//    needs draining at barriers in this kernel.
//
// R21 = R20 with every run_net barrier replaced by:
//     s_waitcnt lgkmcnt(0); sched_barrier(0); s_barrier
// (T4 counted-vmcnt principle, simplest form: weights stay in flight across
// barriers). Single change vs R20 — clean A/B.
// Gates: absmax unchanged (else revert); dur 92-98us; WRITE/FETCH flat.
// ---------------------------------------------------------------------------

using bf16x8 = __attribute__((ext_vector_type(8))) __bf16;
using f32x4  = __attribute__((ext_vector_type(4))) float;

#define LDA 264   // padded activation row stride (bf16)

#define OFFW0 0
#define OFFW1 8192
#define OFFW7 401408
#define WSB_BYTE_OFF 811008   // fp32 bias region
#define OFFB7 1792            // L0..L6 at l*256; L7 at 1792 (16 floats, padded)

#define SCALE_T2 144.26950408889634f      // 100*log2(e)
#define INV_SQRT2 0.70710678118654752f
#define LN2_100 0.0069314718055994531f    // ln2/100

__device__ __forceinline__ float fast_exp2(float x) {
#if __has_builtin(__builtin_amdgcn_exp2f)
    return __builtin_amdgcn_exp2f(x);
#else
    return exp2f(x);
#endif
}

// LDS-only barrier: waves' LDS writes complete (lgkmcnt(0)) before arrival;
// VMEM (weight) loads stay IN FLIGHT across the barrier. All inter-wave
// hazards in this kernel are LDS-side, so this is sufficient ordering.
// sched_barrier(0) pins the asm waitcnt against compiler motion (rule #18).
__device__ __forceinline__ void bar_lds() {
    asm volatile("s_waitcnt lgkmcnt(0)" ::: "memory");
    __builtin_amdgcn_sched_barrier(0);
    __builtin_amdgcn_s_barrier();
    __builtin_amdgcn_sched_barrier(0);
}

// a2 = max(t2,0) + log2(1 + 2^-|t2|)   (t2-domain; scales folded into weights)
// log2(1+e), e in [0,1], as cubic through origin (R20): 1 trans + 5 VALU.
__device__ __forceinline__ float softplus_t2(float t2) {
    float e = fast_exp2(-fabsf(t2));
    float p = __builtin_fmaf(e, 0.20568f, -0.64838f);
    p = __builtin_fmaf(e, p, 1.4427f);
    return fmaxf(t2, 0.0f) + e * p;
}

__device__ __forceinline__ unsigned short bf16_rne(float f) {
    unsigned int u = __float_as_uint(f);
    unsigned int r = u + 0x7FFFu + ((u >> 16) & 1u);
    return (unsigned short)(r >> 16);
}

// ---------------------------------------------------------------------------
// Plain MFMA half (layer 0 only, KK=1). Wave owns ch [wave*32, wave*32+32).
// ---------------------------------------------------------------------------
template <int KK, int NTG>
__device__ __forceinline__ void mfma_group(
    const unsigned short* __restrict__ wfrag,
    const float* __restrict__ bias,
    const unsigned short* act,
    f32x4 (&acc)[2][NTG], int wave, int lane)
{
    const int quad = lane >> 4;
    const int l15  = lane & 15;

#pragma unroll
    for (int i = 0; i < 2; ++i) {
        const int chb = (wave * 2 + i) * 16 + quad * 4;
        const float4 b4 = *(const float4*)(bias + chb);
#pragma unroll
        for (int nt = 0; nt < NTG; ++nt)
            acc[i][nt] = f32x4{b4.x, b4.y, b4.z, b4.w};
    }

    const unsigned short* wbase = wfrag + (wave * 2 * KK * 64 + lane) * 8;

#pragma unroll
    for (int kk = 0; kk < KK; ++kk) {
        bf16x8 bfr[NTG];
#pragma unroll
        for (int nt = 0; nt < NTG; ++nt)
            bfr[nt] = *(const bf16x8*)(act + (nt * 16 + l15) * LDA + kk * 32 + quad * 8);
#pragma unroll
        for (int i = 0; i < 2; ++i) {
            bf16x8 afr = *(const bf16x8*)(wbase + (i * KK + kk) * 512);
#pragma unroll
            for (int nt = 0; nt < NTG; ++nt)
                acc[i][nt] = __builtin_amdgcn_mfma_f32_16x16x32_bf16(afr, bfr[nt], acc[i][nt], 0, 0, 0);
        }
    }
}

// Full epilogue of a group (used where no mfma to hide under).
template <int NTG>
__device__ __forceinline__ void epi_group_full(
    f32x4 (&acc)[2][NTG], unsigned short* act, const float* xst,
    int wave, int lane, bool splice)
{
    const int quad = lane >> 4;
    const int l15  = lane & 15;
#pragma unroll
    for (int i = 0; i < 2; ++i) {
        const int chb = (wave * 2 + i) * 16 + quad * 4;
#pragma unroll
        for (int nt = 0; nt < NTG; ++nt) {
            const int pt = nt * 16 + l15;
            float vv[4];
#pragma unroll
            for (int r = 0; r < 4; ++r)
                vv[r] = softplus_t2(acc[i][nt][r]);
            if (splice && chb == 252) {
                vv[1] = xst[pt * 4 + 0];
                vv[2] = xst[pt * 4 + 1];
                vv[3] = xst[pt * 4 + 2];
            }
            __hip_bfloat162 p01 = __float22bfloat162_rn(float2{vv[0], vv[1]});
            __hip_bfloat162 p23 = __float22bfloat162_rn(float2{vv[2], vv[3]});
            uint2 pk;
            pk.x = *(unsigned int*)&p01;
            pk.y = *(unsigned int*)&p23;
            *(uint2*)(act + pt * LDA + chb) = pk;
        }
    }
}

// ---------------------------------------------------------------------------
// Staggered region: build accX = W.actX + b while retiring accY (other
// group's previous-layer preacts) one slice per kk step (6 slices, kk 0..5).
// Order per kk: bfr ds_reads -> afr loads -> slice VALU (in load shadow) ->
// 6 MFMAs. No forced prefetch: compiler pipelines within its reg budget.
// ---------------------------------------------------------------------------
template <int KK, int NTG>
__device__ __forceinline__ void stag_region(
    const unsigned short* __restrict__ wfrag,
    const float* __restrict__ bias,
    const unsigned short* __restrict__ actX,
    unsigned short* actY,
    f32x4 (&accX)[2][NTG], f32x4 (&accY)[2][NTG],
    const float* xstY, bool splice, int wave, int lane)
{
    const int quad = lane >> 4;
    const int l15  = lane & 15;

#pragma unroll
    for (int i = 0; i < 2; ++i) {
        const int chb = (wave * 2 + i) * 16 + quad * 4;
        const float4 b4 = *(const float4*)(bias + chb);
#pragma unroll
        for (int nt = 0; nt < NTG; ++nt)
            accX[i][nt] = f32x4{b4.x, b4.y, b4.z, b4.w};
    }

    const unsigned short* wbase = wfrag + (wave * 2 * KK * 64 + lane) * 8;

#pragma unroll
    for (int kk = 0; kk < KK; ++kk) {
        bf16x8 bfr[NTG];
#pragma unroll
        for (int nt = 0; nt < NTG; ++nt)
            bfr[nt] = *(const bf16x8*)(actX + (nt * 16 + l15) * LDA + kk * 32 + quad * 8);

        bf16x8 a0 = *(const bf16x8*)(wbase + kk * 512);
        bf16x8 a1 = *(const bf16x8*)(wbase + (KK + kk) * 512);

        if (kk < 2 * NTG) {   // one retired slice of group Y (compile-time idx)
            const int i  = kk & 1;       // constant under full unroll
            const int nt = kk >> 1;
            const int chb = (wave * 2 + i) * 16 + quad * 4;
            const int pt  = nt * 16 + l15;
            float vv[4];
#pragma unroll
            for (int r = 0; r < 4; ++r)
                vv[r] = softplus_t2(accY[i][nt][r]);
            if (splice && chb == 252) {   // ch 253..255 <- raw x
                vv[1] = xstY[pt * 4 + 0];
                vv[2] = xstY[pt * 4 + 1];
                vv[3] = xstY[pt * 4 + 2];
            }
            __hip_bfloat162 p01 = __float22bfloat162_rn(float2{vv[0], vv[1]});
            __hip_bfloat162 p23 = __float22bfloat162_rn(float2{vv[2], vv[3]});
            uint2 pk;
            pk.x = *(unsigned int*)&p01;
            pk.y = *(unsigned int*)&p23;
            *(uint2*)(actY + pt * LDA + chb) = pk;
        }

#pragma unroll
        for (int nt = 0; nt < NTG; ++nt)
            accX[0][nt] = __builtin_amdgcn_mfma_f32_16x16x32_bf16(a0, bfr[nt], accX[0][nt], 0, 0, 0);
#pragma unroll
        for (int nt = 0; nt < NTG; ++nt)
            accX[1][nt] = __builtin_amdgcn_mfma_f32_16x16x32_bf16(a1, bfr[nt], accX[1][nt], 0, 0, 0);
    }
}

// ---------------------------------------------------------------------------
// Layer 7 (256->8) for one 16-pt row block at row0; reduce + CSG + store.
// ---------------------------------------------------------------------------
__device__ __forceinline__ void l7_part(
    const unsigned short* act, const unsigned short* __restrict__ w7,
    const float* __restrict__ wsB, float* __restrict__ out,
    int row0, int ptg0, int npts, int lane)
{
    const int quad = lane >> 4, l15 = lane & 15;
    const float4 b4 = *(const float4*)(wsB + OFFB7 + quad * 4);  // quads>=2: zeros
    f32x4 acc = f32x4{b4.x, b4.y, b4.z, b4.w};
#pragma unroll
    for (int kk = 0; kk < 8; ++kk) {
        bf16x8 bfr = *(const bf16x8*)(act + (row0 + l15) * LDA + kk * 32 + quad * 8);
        bf16x8 afr = *(const bf16x8*)(w7 + (kk * 64 + lane) * 8);
        acc = __builtin_amdgcn_mfma_f32_16x16x32_bf16(afr, bfr, acc, 0, 0, 0);
    }
    // quad0 lanes hold ch0-3, quad1 ch4-7 for pt = row0+l15
    float u0 = __shfl(acc[0], l15 + 16);
    float u1 = __shfl(acc[1], l15 + 16);
    float u2 = __shfl(acc[2], l15 + 16);
    float u3 = __shfl(acc[3], l15 + 16);
    if (quad == 0) {
        const int ptg = ptg0 + l15;
        if (ptg < npts) {
            const float v0 = acc[0], v1 = acc[1], v2 = acc[2], v3 = acc[3];
            const float v4 = u0, v5 = u1, v6 = u2, v7 = u3;
            const float m23   = fminf(v2, v3);
            const float m67   = fmaxf(v6, v7);
            const float m4567 = fminf(fminf(v4, v5), m67);
            const float h     = fmaxf(fmaxf(v0, v1), fmaxf(m23, m4567));
            float* o = out + (long)ptg * 9;
            o[0] = h;
            o[1] = v0; o[2] = v1; o[3] = v2; o[4] = v3;
            o[5] = v4; o[6] = v5; o[7] = v6; o[8] = v7;
        }
    }
}

// ---------------------------------------------------------------------------
// Full network for one tile of 2*NTG*16 points (NTG=3 -> 96, NTG=1 -> 32),
// two staggered in-place groups A (rows 0..NTG*16) and B (rest). Schedule:
//   stage; bar
//   mfma_A(0); bar
//   mfma_B(0); epi_A(0); bar
//   l=1..6:  stag[mfma_A(l) + slices of accB(l-1)]; bar
//            stag[mfma_B(l) + slices of accA(l)];   bar
//   [L7(A) || epi_B(6)]; bar;  L7(B)
// All barriers are LDS-only (bar_lds): vmcnt stays in flight.
// ---------------------------------------------------------------------------
template <int NTG>
__device__ __forceinline__ void run_net(
    const float* __restrict__ x, float* __restrict__ out,
    const unsigned short* __restrict__ wsW, const float* __restrict__ wsB,
    unsigned short* act, float* xst,
    int base_pt, int npts, int tid)
{
    const int wave = tid >> 6, lane = tid & 63;

    // stage x into act channels 0..2, zero-pad to 32 (K-pad for layer 0)
    for (int i = tid; i < 2 * NTG * 16 * 32; i += 512) {
        const int pt = i >> 5, ch = i & 31;
        const int ptg = base_pt + pt;
        float v = 0.0f;
        if (ch < 3 && ptg < npts) v = x[ptg * 3 + ch];
        act[pt * LDA + ch] = bf16_rne(v);
        if (ch < 4) xst[pt * 4 + ch] = (ch < 3) ? v : 0.0f;
    }
    bar_lds();

    unsigned short* actA = act;
    unsigned short* actB = act + NTG * 16 * LDA;
    const float* xstA = xst;
    const float* xstB = xst + NTG * 16 * 4;

    f32x4 accA[2][NTG], accB[2][NTG];

    // layer 0 (KK=1, tiny): A alone, then B with serial epi_A
    mfma_group<1, NTG>(wsW + OFFW0, wsB, actA, accA, wave, lane);
    bar_lds();
    mfma_group<1, NTG>(wsW + OFFW0, wsB, actB, accB, wave, lane);
    epi_group_full<NTG>(accA, actA, xstA, wave, lane, false);
    bar_lds();

    // layers 1..6, two staggered regions each
#pragma unroll 1
    for (int l = 1; l <= 6; ++l) {
        const unsigned short* Wl = wsW + OFFW1 + (l - 1) * 65536;
        const float* bl = wsB + l * 256;

        // mfma_A(l) + retire accB(l-1)  (splice when l-1 == 3)
        stag_region<8, NTG>(Wl, bl, actA, actB, accA, accB, xstB, l == 4, wave, lane);
        bar_lds();

        // mfma_B(l) + retire accA(l)    (splice when l == 3)
        stag_region<8, NTG>(Wl, bl, actB, actA, accB, accA, xstA, l == 3, wave, lane);
        bar_lds();
    }

    // [L7(A) || epi_B(6)]: actA finalized last region; epi writes actB only.
    if (wave < NTG)
        l7_part(act, wsW + OFFW7, wsB, out, wave * 16, base_pt + wave * 16, npts, lane);
    epi_group_full<NTG>(accB, actB, xstB, wave, lane, false);
    bar_lds();

    // L7(B)
    if (wave < NTG)
        l7_part(act, wsW + OFFW7, wsB, out,
                NTG * 16 + wave * 16, base_pt + NTG * 16 + wave * 16, npts, lane);
}

__global__ __launch_bounds__(512, 4)
void nhrep_main(const float* __restrict__ x, float* __restrict__ out,
                const unsigned short* __restrict__ wsW,
                const float* __restrict__ wsB, int npts, int nbig)
{
    __shared__ unsigned short act[96 * LDA];   // 50688 B
    __shared__ float xst[96 * 4];              // 1536 B -> 52224 B total
    const int b = blockIdx.x;
    if (b < nbig) {
        run_net<3>(x, out, wsW, wsB, act, xst, b * 96, npts, threadIdx.x);
    } else {
        run_net<1>(x, out, wsW, wsB, act, xst,
                   nbig * 96 + (b - nbig) * 32, npts, threadIdx.x);
    }
}

// ---------------------------------------------------------------------------
// Fused prepack with scale folding (proven since R4, identity k-mapping).
// Frag (mt,kk,lane,j) = scale(l,k) * W^T[mt*16+(lane&15)][kk*32+(lane>>4)*8+j]
// ---------------------------------------------------------------------------
struct PackArgs {
    const float* W[8];
    const float* b[8];
};

#define TOTAL_FRAGS 50688
#define TOTAL_BIAS  1808

__global__ void prepack_all(PackArgs args, unsigned short* __restrict__ dstW,
                            float* __restrict__ dstB)
{
    const int t = blockIdx.x * blockDim.x + threadIdx.x;
    const int FB[9]  = {0, 1024, 9216, 17408, 25600, 33792, 41984, 50176, 50688};
    const int KKs[8] = {1, 8, 8, 8, 8, 8, 8, 8};
    const int ind[8] = {3, 256, 256, 256, 256, 256, 256, 256};
    const int outd[8]= {256, 256, 256, 253, 256, 256, 256, 8};

    if (t < TOTAL_FRAGS) {
        int l = 0;
        while (t >= FB[l + 1]) ++l;
        const int f    = t - FB[l];
        const int lane = f & 63;
        const int kk   = (f >> 6) % KKs[l];
        const int mt   = f / (64 * KKs[l]);
        const int o    = mt * 16 + (lane & 15);
        const int kb   = kk * 32 + (lane >> 4) * 8;
        const float* W = args.W[l];
        const int in_d = ind[l], out_d = outd[l];

        unsigned short v[8];
#pragma unroll
        for (int j = 0; j < 8; ++j) {
            const int k = kb + j;
            float w = 0.0f;
            if (k < in_d && o < out_d) {
                float sc = 1.0f;
                if (l == 0) sc = SCALE_T2;
                else if (l == 4) sc = (k < 253) ? INV_SQRT2 : (SCALE_T2 * INV_SQRT2);
                else if (l == 7) sc = LN2_100;
                w = W[k * out_d + o] * sc;
            }
            unsigned int u = __float_as_uint(w);
            v[j] = (unsigned short)((u + 0x7FFFu + ((u >> 16) & 1u)) >> 16);
        }
        uint4 p;
        p.x = (unsigned int)v[0] | ((unsigned int)v[1] << 16);
        p.y = (unsigned int)v[2] | ((unsigned int)v[3] << 16);
        p.z = (unsigned int)v[4] | ((unsigned int)v[5] << 16);
        p.w = (unsigned int)v[6] | ((unsigned int)v[7] << 16);
        *(uint4*)(dstW + (long)t * 8) = p;
    } else if (t < TOTAL_FRAGS + TOTAL_BIAS) {
        const int u = t - TOTAL_FRAGS;
        const int l = (u < 1792) ? (u >> 8) : 7;
        const int idx = (l < 7) ? (u & 255) : (u - 1792);
        const float sc = (l < 7) ? SCALE_T2 : 1.0f;   // b7 stays in output units
        dstB[u] = (idx < outd[l]) ? args.b[l][idx] * sc : 0.0f;
    }
}

extern "C" void kernel_launch(void* const* d_in, const int* in_sizes, int n_in,
                              void* d_out, int out_size, void* d_ws, size_t ws_size,
                              hipStream_t stream)
{
    const float* x = (const float*)d_in[0];
    unsigned short* wsW = (unsigned short*)d_ws;
    float* wsB = (float*)((char*)d_ws + WSB_BYTE_OFF);

    PackArgs pa;
    for (int l = 0; l < 8; ++l) {
        pa.W[l] = (const float*)d_in[1 + 2 * l];
        pa.b[l] = (const float*)d_in[2 + 2 * l];
    }
    const int ptot = TOTAL_FRAGS + TOTAL_BIAS;
    prepack_all<<<(ptot + 255) / 256, 256, 0, stream>>>(pa, wsW, wsB);

    const int npts = in_sizes[0] / 3;            // 100000
    // Mixed grid: 96-pt blocks for the bulk, 32-pt blocks for the drain tail.
    int nbig, nsmall;
    const int tail_pts = 16384;
    if (npts > tail_pts) {
        nbig = (npts - tail_pts + 95) / 96;      // 871
        const int base_small = nbig * 96;
        nsmall = (npts - base_small + 31) / 32;  // 512
    } else {
        nbig = 0;
        nsmall = (npts + 31) / 32;
    }
    nhrep_main<<<nbig + nsmall, 512, 0, stream>>>(x, (float*)d_out, wsW, wsB,
                                                  npts, nbig);
}